// Round 10
// baseline (1365.063 us; speedup 1.0000x reference)
//
#include <hip/hip_runtime.h>
#include <math.h>

#define N_TOKENS 32768
#define DIM      4096
#define NE       64
#define TM       64              // tokens per block
#define BK       128             // K-chunk
#define KHALF    (DIM / 2)       // 2048
#define NBLK_MAIN (N_TOKENS / TM * 2)   // 1024 (x2 for K-split)
#define NBLK_POST (N_TOKENS / 256)      // 128
#define EPS_GAP  2e-3f
#define REFINE_BLOCKS 1024

// d_out layout (float32 elements):
//   [0, 65536)        weights  [N_TOKENS][2]
//   [65536, 131072)   indices  [N_TOKENS][2]  stored as float
//   [131072, 131136)  new_bias [64]
//
// d_ws layout (4-byte units):
//   [0, 64)              ews_refine[64]  (float, zeroed per call)
//   [64]                 worklist count  (uint, zeroed per call)
//   [128, 8320)          per-post-block expert partials [128][64] (float)
//   [16384, 49152)       worklist token ids (int)
//   [65664, 327808)      W fragments: whi then wlo (bf16, 512KB each)
//   [524288, 4718592)    partial scores psc[2][N_TOKENS][64] (f32, 16.8MB)
//   [5000000, 6500000)   probe checksums
//   [8388608, 142606336) probe_ws read region (512MB of poison, read-only)
#define WOFF     65664
#define WL_OFF   16384
#define PART_OFF 128
#define PSC_OFF  524288
#define WFRAG_ELEMS (512 * 512)   // 262144 bf16 per plane

typedef __bf16 bf16x8 __attribute__((ext_vector_type(8)));
typedef float  f32x16 __attribute__((ext_vector_type(16)));

// Convert W [64][4096] f32 -> fragment-ordered bf16 hi/lo.
__global__ __launch_bounds__(256) void prep_w(
    const float* __restrict__ w, float* __restrict__ ws)
{
    __bf16* whi = (__bf16*)(ws + WOFF);
    __bf16* wlo = whi + WFRAG_ELEMS;
    const int tid  = blockIdx.x * 256 + threadIdx.x;  // 0..32767
    const int f    = tid >> 6, lane = tid & 63;
    const int nt   = f & 1,    K16  = f >> 1;
    const int e    = nt * 32 + (lane & 31);
    const int k    = K16 * 16 + (lane >> 5) * 8;
    const float4 a = *(const float4*)(w + (size_t)e * DIM + k);
    const float4 b = *(const float4*)(w + (size_t)e * DIM + k + 4);
    const float v[8] = {a.x, a.y, a.z, a.w, b.x, b.y, b.z, b.w};
    __bf16 h[8], l[8];
    #pragma unroll
    for (int i = 0; i < 8; ++i) {
        h[i] = (__bf16)v[i];
        l[i] = (__bf16)(v[i] - (float)h[i]);
    }
    *(bf16x8*)(whi + (size_t)tid * 8) = *(bf16x8*)h;
    *(bf16x8*)(wlo + (size_t)tid * 8) = *(bf16x8*)l;
}

__device__ __forceinline__ unsigned pack_pair(float f0, float f1, float& r0, float& r1) {
    const unsigned u0 = __float_as_uint(f0), u1 = __float_as_uint(f1);
    const unsigned h0 = u0 & 0xFFFF0000u,   h1 = u1 & 0xFFFF0000u;
    r0 = f0 - __uint_as_float(h0);
    r1 = f1 - __uint_as_float(h1);
    return (u0 >> 16) | h1;
}
__device__ __forceinline__ void cvt_split4(const float4 v, uint2& h, uint2& l) {
    float r0, r1, r2, r3;
    h.x = pack_pair(v.x, v.y, r0, r1);
    h.y = pack_pair(v.z, v.w, r2, r3);
    l.x = (__float_as_uint(r0) >> 16) | (__float_as_uint(r1) & 0xFFFF0000u);
    l.y = (__float_as_uint(r2) >> 16) | (__float_as_uint(r3) & 0xFFFF0000u);
}

// Split-K GEMM (R4 structure, best-so-far): block b = tokens [tb,tb+64),
// K-half kh = b&1. Writes partial scores psc[kh][tok][e].
__global__ __launch_bounds__(256, 4) void gate_main(
    const float* __restrict__ x, float* __restrict__ ws)
{
    __shared__ __align__(16) unsigned char smem[32768];

    const __bf16* whi = (const __bf16*)(ws + WOFF);
    const __bf16* wlo = whi + WFRAG_ELEMS;
    float*        psc = ws + PSC_OFF;

    const int t    = threadIdx.x;
    const int lane = t & 63;
    const int wave = t >> 6;
    const int mt   = wave >> 1;
    const int nt   = wave & 1;
    const int kh   = blockIdx.x & 1;
    const int tb   = (blockIdx.x >> 1) * TM;
    const int kbeg = kh * KHALF;

    const int q     = t & 31;
    const int rbase = t >> 5;

    f32x16 acc0, acc12;
    #pragma unroll
    for (int i = 0; i < 16; ++i) { acc0[i] = 0.f; acc12[i] = 0.f; }

    float4 xv[8];
    #pragma unroll
    for (int j = 0; j < 8; ++j)
        xv[j] = *(const float4*)(x + (size_t)(tb + rbase + 8 * j) * DIM + kbeg + q * 4);

    const int tok0  = mt * 32 + (lane & 31);
    const int klane = lane >> 5;
    const int abase = tok0 * 256;
    const int aswz  = (tok0 & 7) << 4;

    for (int kc = kbeg; kc < kbeg + KHALF; kc += BK) {
        #pragma unroll
        for (int j = 0; j < 8; ++j) {
            const int r = rbase + 8 * j;
            uint2 h, l;
            cvt_split4(xv[j], h, l);
            const int off = r * 256 + ((q * 8) ^ ((r & 7) << 4));
            *(uint2*)(&smem[off])         = h;
            *(uint2*)(&smem[16384 + off]) = l;
        }
        __syncthreads();

        if (kc + BK < kbeg + KHALF) {
            #pragma unroll
            for (int j = 0; j < 8; ++j)
                xv[j] = *(const float4*)(x + (size_t)(tb + rbase + 8 * j) * DIM + kc + BK + q * 4);
        }

        const int K16c = kc >> 4;
        #pragma unroll
        for (int ks = 0; ks < 8; ++ks) {
            const int aoff = abase + ((ks * 32 + klane * 16) ^ aswz);
            const bf16x8 ah = *(const bf16x8*)(&smem[aoff]);
            const bf16x8 al = *(const bf16x8*)(&smem[16384 + aoff]);
            const size_t bidx = ((size_t)((K16c + ks) * 2 + nt) * 64 + lane) * 8;
            const bf16x8 bh = *(const bf16x8*)(whi + bidx);
            const bf16x8 bl = *(const bf16x8*)(wlo + bidx);
            acc0  = __builtin_amdgcn_mfma_f32_32x32x16_bf16(ah, bh, acc0,  0, 0, 0);
            acc12 = __builtin_amdgcn_mfma_f32_32x32x16_bf16(al, bh, acc12, 0, 0, 0);
            acc12 = __builtin_amdgcn_mfma_f32_32x32x16_bf16(ah, bl, acc12, 0, 0, 0);
        }
        __syncthreads();
    }

    const int e = nt * 32 + (lane & 31);
    float* base = psc + (size_t)kh * N_TOKENS * NE;
    #pragma unroll
    for (int r = 0; r < 16; ++r) {
        const int tok = mt * 32 + (r & 3) + 8 * (r >> 2) + 4 * (lane >> 5);
        base[(size_t)(tb + tok) * NE + e] = acc0[r] + acc12[r];
    }
}

// Sum K-halves + bias, top-3 scan, risky-flag or write outputs; expert partials.
__global__ __launch_bounds__(256) void gate_post(
    const float* __restrict__ bias,
    float* __restrict__ out,
    float* __restrict__ ws)
{
    __shared__ float sbias[NE];
    __shared__ float part[NE];
    unsigned* wl_count = (unsigned*)(ws + 64);
    float*    partials = ws + PART_OFF;
    int*      wl       = (int*)(ws + WL_OFF);
    const float* psc   = ws + PSC_OFF;
    const size_t PL    = (size_t)N_TOKENS * NE;

    const int t = threadIdx.x;
    if (t < NE) { sbias[t] = bias[t]; part[t] = 0.f; }
    __syncthreads();

    const int tok = blockIdx.x * 256 + t;
    const float* p = psc + (size_t)tok * NE;

    float v1 = -3e38f, v2 = -3e38f, v3 = -3e38f;
    int   i1 = 0,      i2 = 0;
    #pragma unroll
    for (int g = 0; g < 16; ++g) {
        const float4 a = *(const float4*)(p + g * 4);
        const float4 b = *(const float4*)(p + PL + g * 4);
        float sv4[4] = {a.x + b.x, a.y + b.y, a.z + b.z, a.w + b.w};
        #pragma unroll
        for (int j = 0; j < 4; ++j) {
            const float sv = sv4[j] + sbias[g * 4 + j];
            const int   e  = g * 4 + j;
            if (sv > v1)      { v3 = v2; v2 = v1; i2 = i1; v1 = sv; i1 = e; }
            else if (sv > v2) { v3 = v2; v2 = sv; i2 = e; }
            else if (sv > v3) { v3 = sv; }
        }
    }
    const bool risky = (v1 - v2 < EPS_GAP) || (v2 - v3 < EPS_GAP);
    if (risky) {
        const int pos = (int)atomicAdd(wl_count, 1u);
        wl[pos] = tok;
    } else {
        const float ex = expf(v2 - v1);
        const float w1 = 1.f / (1.f + ex);
        const float w2 = ex * w1;
        const size_t g = (size_t)tok * 2;
        *(float2*)(out + g)                        = make_float2(w1, w2);
        *(float2*)(out + (size_t)N_TOKENS * 2 + g) = make_float2((float)i1, (float)i2);
        atomicAdd(&part[i1], w1);
        atomicAdd(&part[i2], w2);
    }
    __syncthreads();
    if (t < NE) partials[(size_t)blockIdx.x * NE + t] = part[t];
}

// fp64 re-score of near-tie tokens.
__global__ __launch_bounds__(256) void gate_refine(
    const float* __restrict__ x,
    const float* __restrict__ w,
    const float* __restrict__ bias,
    float* __restrict__ out,
    float* __restrict__ ws)
{
    float*          ews_ref  = ws;
    const unsigned* wl_count = (const unsigned*)(ws + 64);
    const int*      wl       = (const int*)(ws + WL_OFF);

    const int t = threadIdx.x;
    const int e = t >> 2;
    const int q = t & 3;
    __shared__ double sc[NE];

    const unsigned count = *wl_count;
    for (unsigned it = blockIdx.x; it < count; it += gridDim.x) {
        const int tok = wl[it];
        const float* xr = x + (size_t)tok * DIM;
        const float* wr = w + (size_t)e * DIM;
        double s = 0.0;
        const int k0 = q * (DIM / 4), k1 = k0 + DIM / 4;
        for (int k = k0; k < k1; k += 4) {
            const float4 a = *(const float4*)(xr + k);
            const float4 b = *(const float4*)(wr + k);
            s += (double)a.x * (double)b.x;
            s += (double)a.y * (double)b.y;
            s += (double)a.z * (double)b.z;
            s += (double)a.w * (double)b.w;
        }
        s += __shfl_xor(s, 1);
        s += __shfl_xor(s, 2);
        if (q == 0) sc[e] = s + (double)bias[e];
        __syncthreads();

        if (t == 0) {
            double v1 = -1e300, v2 = -1e300;
            int i1 = 0, i2 = 0;
            for (int j = 0; j < NE; ++j) {
                const double sv = sc[j];
                if (sv > v1)      { v2 = v1; i2 = i1; v1 = sv; i1 = j; }
                else if (sv > v2) { v2 = sv; i2 = j; }
            }
            const double ex = exp(v2 - v1);
            const double w1 = 1.0 / (1.0 + ex);
            const double w2 = ex * w1;
            const size_t g = (size_t)tok * 2;
            *(float2*)(out + g)                        = make_float2((float)w1, (float)w2);
            *(float2*)(out + (size_t)N_TOKENS * 2 + g) = make_float2((float)i1, (float)i2);
            atomicAdd(&ews_ref[i1], (float)w1);
            atomicAdd(&ews_ref[i2], (float)w2);
        }
        __syncthreads();
    }
}

__global__ void gate_bias(
    const float* __restrict__ bias,
    const float* __restrict__ target,
    const float* __restrict__ ws,
    float* __restrict__ out)
{
    const int e = threadIdx.x;
    const float* partials = ws + PART_OFF;
    float v = ws[e];
    for (int b = 0; b < NBLK_POST; ++b) v += partials[(size_t)b * NE + e];
    float total = v;
    #pragma unroll
    for (int off = 32; off > 0; off >>= 1)
        total += __shfl_xor(total, off);
    const float nb = bias[e] + 0.001f * ((target[e] * total - v) / total);
    out[(size_t)N_TOKENS * 4 + e] = nb;
}

// ================= DIAGNOSTIC PROBES (sacrificial round) =================
// Each: 4 full 512MB passes so duration > the ~320us harness fills and thus
// appears in rocprof top-5 with its own hbm_gbps.

#define PROBE_THREADS (2048 * 256)
#define NF4 ((size_t)N_TOKENS * DIM / 4)   // 33,554,432 float4

// P1: ideal coalesced streaming read of x.
__global__ __launch_bounds__(256) void probe_x(
    const float* __restrict__ x, float* __restrict__ ws)
{
    float4 s = make_float4(0.f, 0.f, 0.f, 0.f);
    const float4* xp = (const float4*)x;
    for (int pass = 0; pass < 4; ++pass) {
        const size_t base = (size_t)((blockIdx.x + pass * 517u) & 2047u) * 256 + threadIdx.x;
        #pragma unroll 4
        for (size_t i = base; i < NF4; i += PROBE_THREADS) {
            const float4 v = xp[i];
            s.x += v.x; s.y += v.y; s.z += v.z; s.w += v.w;
        }
    }
    ws[5000000 + blockIdx.x * 256 + threadIdx.x] = s.x + s.y + s.z + s.w;
}

// P1b: identical pattern on an untouched 512MB region of d_ws (poison data).
__global__ __launch_bounds__(256) void probe_ws(float* __restrict__ ws)
{
    float4 s = make_float4(0.f, 0.f, 0.f, 0.f);
    const float4* wp = (const float4*)(ws + 8388608);   // byte offset 32MB
    for (int pass = 0; pass < 4; ++pass) {
        const size_t base = (size_t)((blockIdx.x + pass * 517u) & 2047u) * 256 + threadIdx.x;
        #pragma unroll 4
        for (size_t i = base; i < NF4; i += PROBE_THREADS) {
            const float4 v = wp[i];
            s.x += v.x; s.y += v.y; s.z += v.z; s.w += v.w;
        }
    }
    ws[5600000 + blockIdx.x * 256 + threadIdx.x] = s.x + s.y + s.z + s.w;
}

// P2: x read in exactly gate_main's staging pattern (no LDS, no compute).
__global__ __launch_bounds__(256) void probe_stage(
    const float* __restrict__ x, float* __restrict__ ws)
{
    const int t = threadIdx.x;
    float4 s = make_float4(0.f, 0.f, 0.f, 0.f);
    for (int pass = 0; pass < 4; ++pass) {
        const int b  = (int)((blockIdx.x + pass * 257u) & 1023u);
        const int kh = b & 1;
        const int tb = (b >> 1) * TM;
        const float* xr = x + (size_t)tb * DIM + kh * KHALF;
        for (int kc = 0; kc < KHALF; kc += BK) {
            #pragma unroll
            for (int j = 0; j < 8; ++j) {
                const float4 v = *(const float4*)(
                    xr + (size_t)((t >> 5) + 8 * j) * DIM + kc + (t & 31) * 4);
                s.x += v.x; s.y += v.y; s.z += v.z; s.w += v.w;
            }
        }
    }
    ws[6200000 + blockIdx.x * 256 + t] = s.x + s.y + s.z + s.w;
}

extern "C" void kernel_launch(void* const* d_in, const int* in_sizes, int n_in,
                              void* d_out, int out_size, void* d_ws, size_t ws_size,
                              hipStream_t stream) {
    const float* x      = (const float*)d_in[0];
    const float* w      = (const float*)d_in[1];
    const float* bias   = (const float*)d_in[2];
    const float* target = (const float*)d_in[3];
    float* out = (float*)d_out;
    float* ws  = (float*)d_ws;

    hipMemsetAsync(ws, 0, 128 * sizeof(float), stream);   // ews_ref + wl_count
    prep_w     <<<128, 256, 0, stream>>>(w, ws);
    gate_main  <<<NBLK_MAIN, 256, 0, stream>>>(x, ws);
    gate_post  <<<NBLK_POST, 256, 0, stream>>>(bias, out, ws);
    gate_refine<<<REFINE_BLOCKS, 256, 0, stream>>>(x, w, bias, out, ws);
    gate_bias  <<<1, 64, 0, stream>>>(bias, target, ws, out);

    // diagnostics (read-only w.r.t. outputs; deterministic)
    probe_x    <<<2048, 256, 0, stream>>>(x, ws);
    probe_ws   <<<2048, 256, 0, stream>>>(ws);
    probe_stage<<<1024, 256, 0, stream>>>(x, ws);
}

// Round 11
// 292.673 us; speedup vs baseline: 4.6641x; 4.6641x over previous
//
#include <hip/hip_runtime.h>
#include <math.h>

#define N_TOKENS 32768
#define DIM      4096
#define NE       64
#define TM       32              // tokens per block
#define BKF      256             // floats per chunk per row = 1 KB
#define NCH      (DIM / BKF)     // 16 chunks
#define NBLK     (N_TOKENS / TM) // 1024
#define EPS_GAP  2e-3f
#define REFINE_BLOCKS 1024

// d_out layout (float32 elements):
//   [0, 65536)        weights  [N_TOKENS][2]
//   [65536, 131072)   indices  [N_TOKENS][2]  stored as float
//   [131072, 131136)  new_bias [64]
//
// d_ws layout (float units):
//   [0, 64)            ews_refine[64] (zeroed per call)
//   [64]               worklist count (uint, zeroed per call)
//   [128, 65664)       per-block expert partials [1024][64]
//   [65664, 98432)     worklist token ids (int)
//   [98432, 622720)    packed W frags: [c][nt][kh][hl][j][lane] 16B units
#define PART_OFF 128
#define WL_OFF   65664
#define WPK_OFF  98432

typedef __bf16 bf16x8 __attribute__((ext_vector_type(8)));
typedef float  f32x16 __attribute__((ext_vector_type(16)));

#define SB0() __builtin_amdgcn_sched_barrier(0)
#define BAR() __builtin_amdgcn_s_barrier()

// Pack W [64][4096] f32 -> bf16 hi/lo fragments in gate_main consumption
// order: idx = ((((c*2+nt)*2+kh)*2+hl)*8 + j)*64 + lane.
// Content: e = nt*32+(lane&31); k16 = c*16+kh*8+j; k = k16*16+(lane>>5)*8.
__global__ __launch_bounds__(256) void prep_w(
    const float* __restrict__ w, float* __restrict__ ws)
{
    const int tid  = blockIdx.x * 256 + threadIdx.x;   // 0..65535
    const int lane = tid & 63;
    const int j    = (tid >> 6) & 7;
    const int hl   = (tid >> 9) & 1;
    const int kh   = (tid >> 10) & 1;
    const int nt   = (tid >> 11) & 1;
    const int c    = tid >> 12;                        // 0..15
    const int e    = nt * 32 + (lane & 31);
    const int k    = (c * 16 + kh * 8 + j) * 16 + (lane >> 5) * 8;
    const float4 a = *(const float4*)(w + (size_t)e * DIM + k);
    const float4 b = *(const float4*)(w + (size_t)e * DIM + k + 4);
    const float v[8] = {a.x, a.y, a.z, a.w, b.x, b.y, b.z, b.w};
    __bf16 hv[8], lv[8];
    #pragma unroll
    for (int i = 0; i < 8; ++i) {
        hv[i] = (__bf16)v[i];
        lv[i] = (__bf16)(v[i] - (float)hv[i]);
    }
    ((bf16x8*)(ws + WPK_OFF))[tid] = hl ? *(bf16x8*)lv : *(bf16x8*)hv;
}

// ---- f32 -> bf16 hi/lo via truncation bit-ops ----
__device__ __forceinline__ unsigned pack_pair(float f0, float f1, float& r0, float& r1) {
    const unsigned u0 = __float_as_uint(f0), u1 = __float_as_uint(f1);
    const unsigned h0 = u0 & 0xFFFF0000u,   h1 = u1 & 0xFFFF0000u;
    r0 = f0 - __uint_as_float(h0);
    r1 = f1 - __uint_as_float(h1);
    return (u0 >> 16) | h1;
}
__device__ __forceinline__ void cvt8(const float4 a, const float4 b, uint4& h, uint4& l) {
    float r0, r1, r2, r3, r4, r5, r6, r7;
    h.x = pack_pair(a.x, a.y, r0, r1);
    h.y = pack_pair(a.z, a.w, r2, r3);
    h.z = pack_pair(b.x, b.y, r4, r5);
    h.w = pack_pair(b.z, b.w, r6, r7);
    l.x = (__float_as_uint(r0) >> 16) | (__float_as_uint(r1) & 0xFFFF0000u);
    l.y = (__float_as_uint(r2) >> 16) | (__float_as_uint(r3) & 0xFFFF0000u);
    l.z = (__float_as_uint(r4) >> 16) | (__float_as_uint(r5) & 0xFFFF0000u);
    l.w = (__float_as_uint(r6) >> 16) | (__float_as_uint(r7) & 0xFFFF0000u);
}

__device__ __forceinline__ void gload_lds16(const float* g, float* lds) {
    __builtin_amdgcn_global_load_lds(
        (const __attribute__((address_space(1))) unsigned*)g,
        (__attribute__((address_space(3))) unsigned*)lds, 16, 0, 0);
}

// R9 structure + PER-BLOCK K-PHASE OFFSET (the round-11 variable):
// block processes chunks in order c_i = (i + phase) & 15, phase = blockIdx&15,
// decorrelating the machine-wide column sweep (DRAM page/channel locality).
// FIFO per iter: [B_c(16), s_{c_{i+1}}(8)] -> vmcnt(8) keeps s_{next} live.
__global__ __launch_bounds__(256) void gate_main(
    const float* __restrict__ x, const float* __restrict__ bias,
    float* __restrict__ out, float* __restrict__ ws)
{
    __shared__ __align__(16) float xs[2][TM * BKF];   // 2 x 32 KB
    __shared__ float sc[TM][68];
    __shared__ float part[NE];
    __shared__ float sbias[NE];

    const bf16x8* wb   = (const bf16x8*)(ws + WPK_OFF);
    unsigned* wl_count = (unsigned*)(ws + 64);
    float*    partials = ws + PART_OFF;
    int*      wl       = (int*)(ws + WL_OFF);

    const int t     = threadIdx.x;
    const int lane  = t & 63;
    const int wave  = t >> 6;
    const int nt    = wave & 1;
    const int kh    = wave >> 1;
    const int tb    = blockIdx.x * TM;
    const int phase = blockIdx.x & 15;
    const int l31   = lane & 31, lhi = lane >> 5;

    if (t < NE) { sbias[t] = bias[t]; part[t] = 0.f; }

    // stage: wave stages rows [wave*8, wave*8+8); instr i = row wave*8+i.
    // lane l covers stored 16B-slot l; logical slot = l ^ (row&15).
    size_t sofs[8];
    #pragma unroll
    for (int i = 0; i < 8; ++i) {
        const int row = wave * 8 + i;
        sofs[i] = (size_t)(tb + row) * DIM + ((lane ^ (row & 15)) << 2);
    }

    f32x16 acc0, acc12;
    #pragma unroll
    for (int i = 0; i < 16; ++i) { acc0[i] = 0.f; acc12[i] = 0.f; }

    // prologue: stage chunk c_0 -> buf 0
    {
        const int c0 = phase;
        #pragma unroll
        for (int i = 0; i < 8; ++i)
            gload_lds16(x + sofs[i] + (size_t)c0 * BKF,
                        &xs[0][(wave * 8 + i) * BKF]);
    }
    SB0();

    for (int it = 0; it < NCH; ++it) {
        const int c = (it + phase) & 15;
        // ---- issue B_c (16 x 1KB from L2-resident packed W) ----
        const int q = c * 4 + nt * 2 + kh;
        bf16x8 bh[8], bl[8];
        #pragma unroll
        for (int j = 0; j < 8; ++j) bh[j] = wb[(q * 2 + 0) * 512 + j * 64 + lane];
        #pragma unroll
        for (int j = 0; j < 8; ++j) bl[j] = wb[(q * 2 + 1) * 512 + j * 64 + lane];
        SB0();
        // ---- issue stage_{c_{it+1}} into the other buffer ----
        if (it + 1 < NCH) {
            const int cn = (it + 1 + phase) & 15;
            #pragma unroll
            for (int i = 0; i < 8; ++i)
                gload_lds16(x + sofs[i] + (size_t)cn * BKF,
                            &xs[(it + 1) & 1][(wave * 8 + i) * BKF]);
        }
        SB0();
        // drain s_{c_it} + B_c; keep s_{next} (8) in flight
        if (it + 1 < NCH) { asm volatile("s_waitcnt vmcnt(8)" ::: "memory"); }
        else             { asm volatile("s_waitcnt vmcnt(0)" ::: "memory"); }
        SB0(); BAR(); SB0();

        // ---- compute chunk c from buf it&1 (pure LDS/VALU/MFMA) ----
        const float* buf = xs[it & 1];
        #pragma unroll
        for (int j = 0; j < 8; ++j) {
            const int s0 = (kh * 8 + j) * 4 + lhi * 2;        // logical 16B slot
            const float4 fa = *(const float4*)&buf[l31 * BKF + ((s0 ^ (l31 & 15)) << 2)];
            const float4 fb = *(const float4*)&buf[l31 * BKF + (((s0 + 1) ^ (l31 & 15)) << 2)];
            uint4 hh, ll;
            cvt8(fa, fb, hh, ll);
            const bf16x8 ah = __builtin_bit_cast(bf16x8, hh);
            const bf16x8 al = __builtin_bit_cast(bf16x8, ll);
            acc0  = __builtin_amdgcn_mfma_f32_32x32x16_bf16(ah, bh[j], acc0,  0, 0, 0);
            acc12 = __builtin_amdgcn_mfma_f32_32x32x16_bf16(al, bh[j], acc12, 0, 0, 0);
            acc12 = __builtin_amdgcn_mfma_f32_32x32x16_bf16(ah, bl[j], acc12, 0, 0, 0);
        }
        SB0(); BAR(); SB0();    // all waves done reading buf it&1
    }

    // ---- epilogue: merge kh halves in LDS, top-3, outputs ----
    // C/D: col = lane&31 (expert), row = (r&3)+8*(r>>2)+4*lhi (token)
    const int e = nt * 32 + l31;
    if (kh == 0) {
        #pragma unroll
        for (int r = 0; r < 16; ++r) {
            const int tok = (r & 3) + 8 * (r >> 2) + 4 * lhi;
            sc[tok][e] = acc0[r] + acc12[r];
        }
    }
    __syncthreads();
    if (kh == 1) {
        #pragma unroll
        for (int r = 0; r < 16; ++r) {
            const int tok = (r & 3) + 8 * (r >> 2) + 4 * lhi;
            sc[tok][e] += acc0[r] + acc12[r];
        }
    }
    __syncthreads();

    if (t < TM) {
        const int tok = t;
        float v1 = -3e38f, v2 = -3e38f, v3 = -3e38f;
        int   i1 = 0,      i2 = 0;
        #pragma unroll 8
        for (int ei = 0; ei < NE; ++ei) {
            const float s = sc[tok][ei] + sbias[ei];
            if (s > v1)      { v3 = v2; v2 = v1; i2 = i1; v1 = s; i1 = ei; }
            else if (s > v2) { v3 = v2; v2 = s;  i2 = ei; }
            else if (s > v3) { v3 = s; }
        }
        const bool risky = (v1 - v2 < EPS_GAP) || (v2 - v3 < EPS_GAP);
        if (risky) {
            const int pos = (int)atomicAdd(wl_count, 1u);
            wl[pos] = tb + tok;                  // refined later in fp64
        } else {
            const float ex = expf(v2 - v1);      // <= 1
            const float w1 = 1.f / (1.f + ex);
            const float w2 = ex * w1;
            const size_t g = (size_t)(tb + tok) * 2;
            *(float2*)(out + g)                        = make_float2(w1, w2);
            *(float2*)(out + (size_t)N_TOKENS * 2 + g) = make_float2((float)i1, (float)i2);
            atomicAdd(&part[i1], w1);
            atomicAdd(&part[i2], w2);
        }
    }
    __syncthreads();
    if (t < NE) partials[(size_t)blockIdx.x * NE + t] = part[t];
}

// fp64 re-score of near-tie tokens: exact ordering vs the true scores.
__global__ __launch_bounds__(256) void gate_refine(
    const float* __restrict__ x,
    const float* __restrict__ w,
    const float* __restrict__ bias,
    float* __restrict__ out,
    float* __restrict__ ws)
{
    float*          ews_ref  = ws;
    const unsigned* wl_count = (const unsigned*)(ws + 64);
    const int*      wl       = (const int*)(ws + WL_OFF);

    const int t = threadIdx.x;
    const int e = t >> 2;        // expert 0..63
    const int q = t & 3;         // quarter of K
    __shared__ double sc[NE];

    const unsigned count = *wl_count;
    for (unsigned iw = blockIdx.x; iw < count; iw += gridDim.x) {
        const int tok = wl[iw];
        const float* xr = x + (size_t)tok * DIM;
        const float* wr = w + (size_t)e * DIM;
        double s = 0.0;
        const int k0 = q * (DIM / 4), k1 = k0 + DIM / 4;
        for (int k = k0; k < k1; k += 4) {
            const float4 a = *(const float4*)(xr + k);
            const float4 b = *(const float4*)(wr + k);
            s += (double)a.x * (double)b.x;
            s += (double)a.y * (double)b.y;
            s += (double)a.z * (double)b.z;
            s += (double)a.w * (double)b.w;
        }
        s += __shfl_xor(s, 1);
        s += __shfl_xor(s, 2);
        if (q == 0) sc[e] = s + (double)bias[e];
        __syncthreads();

        if (t == 0) {
            double v1 = -1e300, v2 = -1e300;
            int i1 = 0, i2 = 0;
            for (int j = 0; j < NE; ++j) {
                const double sv = sc[j];
                if (sv > v1)      { v2 = v1; i2 = i1; v1 = sv; i1 = j; }
                else if (sv > v2) { v2 = sv; i2 = j; }
            }
            const double ex = exp(v2 - v1);
            const double w1 = 1.0 / (1.0 + ex);
            const double w2 = ex * w1;
            const size_t g = (size_t)tok * 2;
            *(float2*)(out + g)                        = make_float2((float)w1, (float)w2);
            *(float2*)(out + (size_t)N_TOKENS * 2 + g) = make_float2((float)i1, (float)i2);
            atomicAdd(&ews_ref[i1], (float)w1);
            atomicAdd(&ews_ref[i2], (float)w2);
        }
        __syncthreads();
    }
}

__global__ __launch_bounds__(256) void gate_bias(
    const float* __restrict__ bias,
    const float* __restrict__ target,
    const float* __restrict__ ws,
    float* __restrict__ out)
{
    __shared__ float red[4][NE];
    const int t = threadIdx.x;
    const int e = t & 63, seg = t >> 6;
    const float* partials = ws + PART_OFF;
    float v = 0.f;
    for (int b = seg * 256; b < seg * 256 + 256; ++b)
        v += partials[(size_t)b * NE + e];
    red[seg][e] = v;
    __syncthreads();
    if (t < NE) {
        const float vv = red[0][t] + red[1][t] + red[2][t] + red[3][t] + ws[t];
        float total = vv;
        #pragma unroll
        for (int off = 32; off > 0; off >>= 1)
            total += __shfl_xor(total, off);
        const float nb = bias[t] + 0.001f * ((target[t] * total - vv) / total);
        out[(size_t)N_TOKENS * 4 + t] = nb;
    }
}

extern "C" void kernel_launch(void* const* d_in, const int* in_sizes, int n_in,
                              void* d_out, int out_size, void* d_ws, size_t ws_size,
                              hipStream_t stream) {
    const float* x      = (const float*)d_in[0];
    const float* w      = (const float*)d_in[1];
    const float* bias   = (const float*)d_in[2];
    const float* target = (const float*)d_in[3];
    float* out = (float*)d_out;
    float* ws  = (float*)d_ws;

    hipMemsetAsync(ws, 0, 128 * sizeof(float), stream);   // ews_ref + wl_count
    prep_w     <<<256, 256, 0, stream>>>(w, ws);
    gate_main  <<<NBLK, 256, 0, stream>>>(x, bias, out, ws);
    gate_refine<<<REFINE_BLOCKS, 256, 0, stream>>>(x, w, bias, out, ws);
    gate_bias  <<<1, 256, 0, stream>>>(bias, target, ws, out);
}